// Round 13
// baseline (4686.843 us; speedup 1.0000x reference)
//
#include <hip/hip_runtime.h>
#include <math.h>

#define BB 32
#define TT 512
#define FF 1024
#define UU 1024
#define NBLK 64

typedef __attribute__((ext_vector_type(8))) short s8v;    // 8 x bf16 (4 VGPR)
typedef __attribute__((ext_vector_type(4))) float f4v;    // 4 x f32

static __device__ __forceinline__ unsigned short f2bf(float f) {
    unsigned int u = __builtin_bit_cast(unsigned int, f);
    u += 0x7fff + ((u >> 16) & 1);          // RNE
    return (unsigned short)(u >> 16);
}
static __device__ __forceinline__ float bf2f(unsigned short b) {
    unsigned int u = ((unsigned int)b) << 16;
    return __builtin_bit_cast(float, u);
}

// ---- PROVEN data path (R5/R7/R10/R11/R12): device-coherent sc0 sc1 ----
static __device__ __forceinline__ s8v ld_b128_sc(const void* p) {
    s8v r;
    asm volatile("global_load_dwordx4 %0, %1, off sc0 sc1" : "=v"(r) : "v"(p));
    return r;
}
static __device__ __forceinline__ void st_b32_sc(void* p, unsigned int v) {
    asm volatile("global_store_dword %0, %1, off sc0 sc1" :: "v"(p), "v"(v));
}
static __device__ __forceinline__ unsigned ld_u32_sc(const unsigned* p) {
    unsigned r;
    asm volatile("global_load_dword %0, %1, off sc0 sc1\n\ts_waitcnt vmcnt(0)"
                 : "=v"(r) : "v"(p) : "memory");
    return r;
}
// opaque plain load (un-rematerializable): pins weights in VGPRs
static __device__ __forceinline__ s8v ld_b128_pin(const void* p) {
    s8v r;
    asm volatile("global_load_dwordx4 %0, %1, off" : "=v"(r) : "v"(p));
    return r;
}
static __device__ __forceinline__ void vm_drain_schedfence() {
    asm volatile("s_waitcnt vmcnt(0)" ::: "memory");
    __builtin_amdgcn_sched_barrier(0);
}

// ---------------------------------------------------------------------------
__global__ __launch_bounds__(256) void cvt_bf16(
    const float* __restrict__ in, unsigned short* __restrict__ out, int n4)
{
    int i = blockIdx.x * 256 + threadIdx.x;
    if (i < n4) {
        float4 v = ((const float4*)in)[i];
        ushort4 o;
        o.x = f2bf(v.x); o.y = f2bf(v.y); o.z = f2bf(v.z); o.w = f2bf(v.w);
        ((ushort4*)out)[i] = o;
    }
}

// ---------------------------------------------------------------------------
template<int ROWS, int COLS>
__global__ __launch_bounds__(256) void transpose_bf16(
    const float* __restrict__ W, unsigned short* __restrict__ WT)
{
    __shared__ float tl[32][33];
    const int tx = threadIdx.x, ty = threadIdx.y;   // block (32, 8)
    const int bx = blockIdx.x, by = blockIdx.y;
    #pragma unroll
    for (int i = 0; i < 4; ++i) {
        int r = by * 32 + ty + i * 8;
        int c = bx * 32 + tx;
        tl[ty + i * 8][tx] = W[(size_t)r * COLS + c];
    }
    __syncthreads();
    #pragma unroll
    for (int i = 0; i < 4; ++i) {
        int n = bx * 32 + ty + i * 8;
        int k = by * 32 + tx;
        WT[(size_t)n * ROWS + k] = f2bf(tl[tx][ty + i * 8]);
    }
}

// ---------------------------------------------------------------------------
// Precompute GEMM. INTERLEAVE=true (gate matrix): store col j<1024 at 2j,
// col>=1024 at 2(j-1024)+1  ->  (r,u) value pairs adjacent per unit col.
// ---------------------------------------------------------------------------
template<bool INTERLEAVE>
__global__ __launch_bounds__(256) void gemm_xproj(
    const unsigned short* __restrict__ A,    // [M][1024]
    const unsigned short* __restrict__ BT,   // [N][2048]
    unsigned short* __restrict__ C,          // [M][N]
    int N)
{
    __shared__ unsigned short Al[128][72];
    __shared__ unsigned short Bl[128][72];
    const int tid  = threadIdx.x;
    const int lane = tid & 63;
    const int wave = tid >> 6;
    const int l15  = lane & 15;
    const int kg   = lane >> 4;
    const int m0   = blockIdx.y * 128;
    const int n0   = blockIdx.x * 128;
    const int rowOff = (wave >> 1) * 64;
    const int colOff = (wave & 1) * 64;

    f4v acc[4][4];
    #pragma unroll
    for (int m = 0; m < 4; ++m)
        #pragma unroll
        for (int n = 0; n < 4; ++n) acc[m][n] = (f4v){0.f, 0.f, 0.f, 0.f};

    for (int k0 = 0; k0 < 1024; k0 += 64) {
        #pragma unroll
        for (int it = 0; it < 4; ++it) {
            int c = tid + it * 256;
            int r = c >> 3, off = (c & 7) * 8;
            *(s8v*)&Al[r][off] = *(const s8v*)(A + (size_t)(m0 + r) * 1024 + k0 + off);
            *(s8v*)&Bl[r][off] = *(const s8v*)(BT + (size_t)(n0 + r) * 2048 + k0 + off);
        }
        __syncthreads();
        #pragma unroll
        for (int ks = 0; ks < 2; ++ks) {
            s8v a[4], b[4];
            #pragma unroll
            for (int m = 0; m < 4; ++m)
                a[m] = *(const s8v*)&Al[rowOff + m * 16 + l15][ks * 32 + kg * 8];
            #pragma unroll
            for (int n = 0; n < 4; ++n)
                b[n] = *(const s8v*)&Bl[colOff + n * 16 + l15][ks * 32 + kg * 8];
            #pragma unroll
            for (int m = 0; m < 4; ++m)
                #pragma unroll
                for (int n = 0; n < 4; ++n)
                    acc[m][n] = __builtin_amdgcn_mfma_f32_16x16x32_bf16(a[m], b[n], acc[m][n], 0, 0, 0);
        }
        __syncthreads();
    }
    #pragma unroll
    for (int m = 0; m < 4; ++m)
        #pragma unroll
        for (int n = 0; n < 4; ++n)
            #pragma unroll
            for (int i = 0; i < 4; ++i) {
                int row = m0 + rowOff + m * 16 + kg * 4 + i;
                int col = n0 + colOff + n * 16 + l15;
                size_t off = INTERLEAVE
                    ? (size_t)row * N + ((col < 1024) ? col * 2 : (col - 1024) * 2 + 1)
                    : (size_t)row * N + col;
                C[off] = f2bf(acc[m][n][i]);
            }
}

// ---------------------------------------------------------------------------
// Persistent GRU: R12 body + AGGREGATOR-BROADCAST barrier.
//   arrive : one sc1 store of epoch to block-private slot (64 lines, no RMW)
//   agg    : block 0 wave 0 polls all 64 slots via one 64-lane gather/iter
//   release: block 0 stores epoch to go-word; others poll read-only
// ---------------------------------------------------------------------------
__global__ __launch_bounds__(256, 1) void gru_fast(
    const unsigned short* __restrict__ WgT,   // [2048][2048] bf16
    const unsigned short* __restrict__ WcT,   // [1024][2048] bf16
    const unsigned short* __restrict__ Xg2,   // [B*T][2048] bf16, (r,u) interleaved
    const unsigned short* __restrict__ Xcb,   // [B*T][1024] bf16
    const float* __restrict__ bg,             // [2048]
    const float* __restrict__ bc,             // [1024]
    unsigned short* __restrict__ hb,          // [32][1024] bf16
    unsigned short* __restrict__ rhb,         // [32][1024] bf16
    float* __restrict__ out,                  // [B][T][U] f32
    unsigned* __restrict__ bar)               // [0]=go, +1024: slots 128B apart
{
    __shared__ float redg[4][32][32];              // 16 KB (G); C reuses 8 KB
    __shared__ unsigned short wc_l[16 * 1024];     // 32 KB
    const int tid  = threadIdx.x;
    const int lane = tid & 63;
    const int wave = tid >> 6;
    const int l15  = lane & 15;
    const int kg   = lane >> 4;
    const int w    = blockIdx.x;
    const int J    = w * 16;
    const int kb   = wave * 256;

    unsigned* go    = bar;
    unsigned* slots = bar + 1024;             // slot w at +w*32 (128 B apart)

    // ---- cand weights (16 cols, recurrent k) -> LDS, XOR-swizzled ----
    #pragma unroll
    for (int it = 0; it < 8; ++it) {
        int c   = tid + it * 256;
        int col = c >> 7;
        int k   = (c & 127) * 8;
        s8v wv = *(const s8v*)(WcT + (size_t)(J + col) * 2048 + 1024 + k);
        *(s8v*)&wc_l[col * 1024 + (k ^ ((col & 7) << 3))] = wv;
    }
    // ---- gate weights (r cols J, u cols 1024+J) -> pinned VGPRs ----
    s8v bgf[2][8];
    #pragma unroll
    for (int kk = 0; kk < 8; ++kk) {
        bgf[0][kk] = ld_b128_pin(WgT + (size_t)(J + l15) * 2048 + 1024 + kb + kk * 32 + kg * 8);
        bgf[1][kk] = ld_b128_pin(WgT + (size_t)(1024 + J + l15) * 2048 + 1024 + kb + kk * 32 + kg * 8);
    }
    vm_drain_schedfence();

    // epilogue mapping: 2 adjacent cols x 1 batch per thread (32 b x 16 c)
    const int b  = tid >> 3;                  // 0..31
    const int c0 = (tid & 7) * 2;             // 0,2,..,14
    const float2 bgr = { bg[J + c0],        bg[J + c0 + 1] };
    const float2 bgu = { bg[1024 + J + c0], bg[1024 + J + c0 + 1] };
    const float2 bcp = { bc[J + c0],        bc[J + c0 + 1] };

    __syncthreads();                          // wc_l ready

    // aggregator-broadcast barrier
    auto gbar = [&](unsigned ph) {
        asm volatile("s_waitcnt vmcnt(0)" ::: "memory");   // sc1 data at LLC first
        __syncthreads();
        if (wave == 0) {
            if (lane == 0) st_b32_sc(slots + (size_t)w * 32, ph);   // arrive
            if (w == 0) {
                unsigned v;                                          // aggregate
                do { v = ld_u32_sc(slots + (size_t)lane * 32); }
                while (!__all((int)(v >= ph)));
                if (lane == 0) st_b32_sc(go, ph);                    // release
            } else if (lane == 0) {
                while (ld_u32_sc(go) < ph)                           // read-only wait
                    __builtin_amdgcn_s_sleep(1);
            }
        }
        __syncthreads();
    };

    float h0 = 0.f, h1 = 0.f;                 // own h (register-resident)
    float u0 = 0.f, u1 = 0.f;

    for (int t = 0; t < TT; ++t) {
        const size_t bt = (size_t)b * TT + t;
        // ================= phase G: r_J, u_J =================
        ushort4 xgp = *(const ushort4*)(Xg2 + bt * 2048 + (size_t)(J + c0) * 2);
        unsigned xcp = *(const unsigned*)(Xcb + bt * 1024 + J + c0);

        s8v a[2][8];
        #pragma unroll
        for (int m = 0; m < 2; ++m)
            #pragma unroll
            for (int kk = 0; kk < 8; ++kk)
                a[m][kk] = ld_b128_sc(hb + (size_t)(m * 16 + l15) * 1024 + kb + kk * 32 + kg * 8);
        vm_drain_schedfence();

        f4v acc[2][2];
        #pragma unroll
        for (int m = 0; m < 2; ++m)
            #pragma unroll
            for (int n = 0; n < 2; ++n) acc[m][n] = (f4v){0.f, 0.f, 0.f, 0.f};
        #pragma unroll
        for (int kk = 0; kk < 8; ++kk)
            #pragma unroll
            for (int m = 0; m < 2; ++m)
                #pragma unroll
                for (int n = 0; n < 2; ++n)
                    acc[m][n] = __builtin_amdgcn_mfma_f32_16x16x32_bf16(a[m][kk], bgf[n][kk], acc[m][n], 0, 0, 0);

        #pragma unroll
        for (int m = 0; m < 2; ++m)
            #pragma unroll
            for (int n = 0; n < 2; ++n)
                #pragma unroll
                for (int i = 0; i < 4; ++i)
                    redg[wave][m * 16 + kg * 4 + i][n * 16 + l15] = acc[m][n][i];
        __syncthreads();

        {
            float2 pr = {0.f, 0.f}, pu = {0.f, 0.f};
            #pragma unroll
            for (int wv = 0; wv < 4; ++wv) {
                float2 p = *(const float2*)&redg[wv][b][c0];
                float2 q = *(const float2*)&redg[wv][b][16 + c0];
                pr.x += p.x; pr.y += p.y;
                pu.x += q.x; pu.y += q.y;
            }
            pr.x += bf2f(xgp.x) + bgr.x;  pu.x += bf2f(xgp.y) + bgu.x;
            pr.y += bf2f(xgp.z) + bgr.y;  pu.y += bf2f(xgp.w) + bgu.y;
            float r0 = 1.f / (1.f + __expf(-pr.x));
            float r1 = 1.f / (1.f + __expf(-pr.y));
            u0 = 1.f / (1.f + __expf(-pu.x));
            u1 = 1.f / (1.f + __expf(-pu.y));
            unsigned pk = (unsigned)f2bf(r0 * h0) | ((unsigned)f2bf(r1 * h1) << 16);
            st_b32_sc(rhb + (size_t)b * 1024 + J + c0, pk);
        }
        gbar((unsigned)(2 * t + 1));

        // ================= phase C: cand_J + update =================
        s8v ac[2][8];
        #pragma unroll
        for (int m = 0; m < 2; ++m)
            #pragma unroll
            for (int kk = 0; kk < 8; ++kk)
                ac[m][kk] = ld_b128_sc(rhb + (size_t)(m * 16 + l15) * 1024 + kb + kk * 32 + kg * 8);
        vm_drain_schedfence();

        f4v acc2[2];
        acc2[0] = (f4v){0.f, 0.f, 0.f, 0.f};
        acc2[1] = (f4v){0.f, 0.f, 0.f, 0.f};
        #pragma unroll
        for (int kk = 0; kk < 8; ++kk) {
            int k = kb + kk * 32 + kg * 8;
            s8v bcf = *(const s8v*)&wc_l[l15 * 1024 + (k ^ ((l15 & 7) << 3))];
            #pragma unroll
            for (int m = 0; m < 2; ++m)
                acc2[m] = __builtin_amdgcn_mfma_f32_16x16x32_bf16(ac[m][kk], bcf, acc2[m], 0, 0, 0);
        }
        float* redc = (float*)redg;           // [4][32][16]
        #pragma unroll
        for (int m = 0; m < 2; ++m)
            #pragma unroll
            for (int i = 0; i < 4; ++i)
                redc[((size_t)wave * 32 + m * 16 + kg * 4 + i) * 16 + l15] = acc2[m][i];
        __syncthreads();

        {
            float2 pc = {0.f, 0.f};
            #pragma unroll
            for (int wv = 0; wv < 4; ++wv) {
                float2 p = *(const float2*)&redc[((size_t)wv * 32 + b) * 16 + c0];
                pc.x += p.x; pc.y += p.y;
            }
            float cv0 = pc.x + bf2f((unsigned short)(xcp & 0xffff)) + bcp.x;
            float cv1 = pc.y + bf2f((unsigned short)(xcp >> 16)) + bcp.y;
            cv0 = fminf(fmaxf(cv0, -15.f), 15.f);
            cv1 = fminf(fmaxf(cv1, -15.f), 15.f);
            float e0 = __expf(2.f * cv0), e1 = __expf(2.f * cv1);
            float t0 = (e0 - 1.f) / (e0 + 1.f);
            float t1 = (e1 - 1.f) / (e1 + 1.f);
            h0 = u0 * h0 + (1.f - u0) * t0;
            h1 = u1 * h1 + (1.f - u1) * t1;
            st_b32_sc(hb + (size_t)b * 1024 + J + c0,
                      (unsigned)f2bf(h0) | ((unsigned)f2bf(h1) << 16));
            *(float2*)(out + bt * 1024 + J + c0) = make_float2(h0, h1);
        }
        if (t + 1 < TT) gbar((unsigned)(2 * t + 2));
    }
}

// ===========================================================================
// Fallback per-step kernels (round-2, verified) — used only if ws too small.
// ===========================================================================
__global__ __launch_bounds__(256) void gru_gates2(
    const unsigned short* __restrict__ hb, const unsigned short* __restrict__ WgT,
    const unsigned short* __restrict__ Xgb, const float* __restrict__ bg,
    const float* __restrict__ h, unsigned short* __restrict__ rhb,
    float* __restrict__ ubuf, int t)
{
    __shared__ unsigned short hb_l[32][1032];
    __shared__ unsigned short Wl[16][1032];
    __shared__ float red[4][32][16];
    const int tid = threadIdx.x, lane = tid & 63, wave = tid >> 6;
    const int l15 = lane & 15, kg = lane >> 4;
    const int j0 = blockIdx.x * 16;
    #pragma unroll
    for (int it = 0; it < 16; ++it) {
        int c = tid + it * 256; int r = c >> 7, off = (c & 127) * 8;
        *(s8v*)&hb_l[r][off] = *(const s8v*)(hb + (size_t)r * 1024 + off);
    }
    #pragma unroll
    for (int it = 0; it < 8; ++it) {
        int c = tid + it * 256; int r = c >> 7, off = (c & 127) * 8;
        *(s8v*)&Wl[r][off] = *(const s8v*)(WgT + (size_t)(j0 + r) * 2048 + 1024 + off);
    }
    __syncthreads();
    f4v acc0 = (f4v){0.f,0.f,0.f,0.f}, acc1 = (f4v){0.f,0.f,0.f,0.f};
    const int kbase = wave * 256;
    #pragma unroll
    for (int kk = 0; kk < 8; ++kk) {
        int k = kbase + kk * 32 + kg * 8;
        s8v a0 = *(const s8v*)&hb_l[l15][k];
        s8v a1 = *(const s8v*)&hb_l[16 + l15][k];
        s8v bv = *(const s8v*)&Wl[l15][k];
        acc0 = __builtin_amdgcn_mfma_f32_16x16x32_bf16(a0, bv, acc0, 0, 0, 0);
        acc1 = __builtin_amdgcn_mfma_f32_16x16x32_bf16(a1, bv, acc1, 0, 0, 0);
    }
    #pragma unroll
    for (int i = 0; i < 4; ++i) {
        red[wave][kg * 4 + i][l15] = acc0[i];
        red[wave][16 + kg * 4 + i][l15] = acc1[i];
    }
    __syncthreads();
    for (int e = tid; e < 512; e += 256) {
        int b = e >> 4, col = e & 15;
        int j = j0 + col;
        float pre = red[0][b][col] + red[1][b][col] + red[2][b][col] + red[3][b][col];
        pre += bf2f(Xgb[((size_t)b * TT + t) * 2048 + j]) + bg[j];
        float s = 1.f / (1.f + __expf(-pre));
        if (j < UU) rhb[b * UU + j] = f2bf(s * h[b * UU + j]);
        else        ubuf[b * UU + (j - UU)] = s;
    }
}

__global__ __launch_bounds__(256) void gru_cand2(
    const unsigned short* __restrict__ rhb, const unsigned short* __restrict__ WcT,
    const unsigned short* __restrict__ Xcb, const float* __restrict__ bc,
    const float* __restrict__ ubuf, float* __restrict__ h,
    unsigned short* __restrict__ hb, float* __restrict__ out, int t)
{
    __shared__ unsigned short rh_l[32][1032];
    __shared__ unsigned short Wl[16][1032];
    __shared__ float red[4][32][16];
    const int tid = threadIdx.x, lane = tid & 63, wave = tid >> 6;
    const int l15 = lane & 15, kg = lane >> 4;
    const int j0 = blockIdx.x * 16;
    #pragma unroll
    for (int it = 0; it < 16; ++it) {
        int c = tid + it * 256; int r = c >> 7, off = (c & 127) * 8;
        *(s8v*)&rh_l[r][off] = *(const s8v*)(rhb + (size_t)r * 1024 + off);
    }
    #pragma unroll
    for (int it = 0; it < 8; ++it) {
        int c = tid + it * 256; int r = c >> 7, off = (c & 127) * 8;
        *(s8v*)&Wl[r][off] = *(const s8v*)(WcT + (size_t)(j0 + r) * 2048 + 1024 + off);
    }
    __syncthreads();
    f4v acc0 = (f4v){0.f,0.f,0.f,0.f}, acc1 = (f4v){0.f,0.f,0.f,0.f};
    const int kbase = wave * 256;
    #pragma unroll
    for (int kk = 0; kk < 8; ++kk) {
        int k = kbase + kk * 32 + kg * 8;
        s8v a0 = *(const s8v*)&rh_l[l15][k];
        s8v a1 = *(const s8v*)&rh_l[16 + l15][k];
        s8v bv = *(const s8v*)&Wl[l15][k];
        acc0 = __builtin_amdgcn_mfma_f32_16x16x32_bf16(a0, bv, acc0, 0, 0, 0);
        acc1 = __builtin_amdgcn_mfma_f32_16x16x32_bf16(a1, bv, acc1, 0, 0, 0);
    }
    #pragma unroll
    for (int i = 0; i < 4; ++i) {
        red[wave][kg * 4 + i][l15] = acc0[i];
        red[wave][16 + kg * 4 + i][l15] = acc1[i];
    }
    __syncthreads();
    for (int e = tid; e < 512; e += 256) {
        int b = e >> 4, col = e & 15;
        int j = j0 + col;
        float pre = red[0][b][col] + red[1][b][col] + red[2][b][col] + red[3][b][col];
        pre += bf2f(Xcb[((size_t)b * TT + t) * 1024 + j]) + bc[j];
        float cv = tanhf(pre);
        float u  = ubuf[b * UU + j];
        float hvv = h[b * UU + j];
        float hn = u * hvv + (1.f - u) * cv;
        h[b * UU + j]  = hn;
        hb[b * UU + j] = f2bf(hn);
        out[((size_t)b * TT + t) * UU + j] = hn;
    }
}

// ===========================================================================
extern "C" void kernel_launch(void* const* d_in, const int* in_sizes, int n_in,
                              void* d_out, int out_size, void* d_ws, size_t ws_size,
                              hipStream_t stream) {
    const float* x  = (const float*)d_in[0];
    const float* Wg = (const float*)d_in[1];
    const float* bg = (const float*)d_in[2];
    const float* Wc = (const float*)d_in[3];
    const float* bc = (const float*)d_in[4];
    float* out = (float*)d_out;

    const size_t XB_B  = (size_t)BB * TT * FF * 2;
    const size_t WGT_B = (size_t)2 * UU * (FF + UU) * 2;
    const size_t WCT_B = (size_t)UU * (FF + UU) * 2;
    const size_t XG_B  = (size_t)BB * TT * 2 * UU * 2;
    const size_t XC_B  = (size_t)BB * TT * UU * 2;
    const size_t H_B   = (size_t)BB * UU * 4;
    const size_t HB_B  = (size_t)BB * UU * 2;
    const size_t BAR_B = 16384;
    const size_t NEED  = XB_B + WGT_B + WCT_B + XG_B + XC_B + H_B + HB_B * 2 + H_B + BAR_B;

    char* p = (char*)d_ws;
    unsigned short* xb  = (unsigned short*)p;            p += XB_B;
    unsigned short* WgT = (unsigned short*)p;            p += WGT_B;
    unsigned short* WcT = (unsigned short*)p;            p += WCT_B;
    unsigned short* Xgb = (unsigned short*)p;            p += XG_B;   // interleaved for persistent
    unsigned short* Xcb = (unsigned short*)p;            p += XC_B;
    float*          h   = (float*)p;                     p += H_B;   // fallback only
    unsigned short* hb  = (unsigned short*)p;            p += HB_B;
    unsigned short* rhb = (unsigned short*)p;            p += HB_B;
    float*          ub  = (float*)p;                     p += H_B;   // fallback only
    unsigned*       bar = (unsigned*)p;                  p += BAR_B;

    const bool persistent = (ws_size >= NEED);

    // ---- one-time prep ----
    cvt_bf16<<<(BB * TT * FF / 4 + 255) / 256, 256, 0, stream>>>(x, xb, BB * TT * FF / 4);
    transpose_bf16<FF + UU, 2 * UU><<<dim3(64, 64), dim3(32, 8), 0, stream>>>(Wg, WgT);
    transpose_bf16<FF + UU, UU>    <<<dim3(32, 64), dim3(32, 8), 0, stream>>>(Wc, WcT);
    if (persistent)
        gemm_xproj<true><<<dim3(2 * UU / 128, BB * TT / 128), 256, 0, stream>>>(xb, WgT, Xgb, 2 * UU);
    else
        gemm_xproj<false><<<dim3(2 * UU / 128, BB * TT / 128), 256, 0, stream>>>(xb, WgT, Xgb, 2 * UU);
    gemm_xproj<false><<<dim3(UU / 128, BB * TT / 128), 256, 0, stream>>>(xb, WcT, Xcb, UU);
    hipMemsetAsync(h,   0, H_B,   stream);
    hipMemsetAsync(hb,  0, HB_B,  stream);
    hipMemsetAsync(bar, 0, BAR_B, stream);

    if (persistent) {
        gru_fast<<<NBLK, 256, 0, stream>>>(WgT, WcT, Xgb, Xcb, bg, bc,
                                           hb, rhb, out, bar);
    } else {
        for (int t = 0; t < TT; ++t) {
            gru_gates2<<<128, 256, 0, stream>>>(hb, WgT, Xgb, bg, h, rhb, ub, t);
            gru_cand2 <<< 64, 256, 0, stream>>>(rhb, WcT, Xcb, bc, ub, h, hb, out, t);
        }
    }
}